// Round 9
// baseline (2281.969 us; speedup 1.0000x reference)
//
#include <hip/hip_runtime.h>
#include <math.h>

#define NB   16
#define NN   16384
#define LDIM 512
#define DDIM 128
#define HIDD 128
#define NCLS 3
#define KCAP 256
#define CCAP 1024
#define ROWB 8
#define EPSV 1e-8f
#define DELTA 0.02f

typedef float  f32x4  __attribute__((ext_vector_type(4)));
typedef int    i32x4  __attribute__((ext_vector_type(4)));
typedef unsigned u32x2 __attribute__((ext_vector_type(2)));
typedef __bf16 bf16x8 __attribute__((ext_vector_type(8)));
typedef unsigned long long u64;

__device__ __forceinline__ int get_k(const int* kp) {
    int k = kp[0];
    if (k < 1 || k > NN) {
        float f = __int_as_float(k);
        if (f >= 1.0f && f <= (float)NN) k = (int)f;
        else k = 70;
    }
    if (k > NN) k = NN;
    return k;
}

__device__ __forceinline__ unsigned okey(float f) {
    unsigned u = __float_as_uint(f);
    return (u & 0x80000000u) ? ~u : (u | 0x80000000u);
}
__device__ __forceinline__ float inv_okey(unsigned k) {
    unsigned u = (k & 0x80000000u) ? (k & 0x7FFFFFFFu) : ~k;
    return __uint_as_float(u);
}

// pack two fp32 -> two RNE bf16 in one u32 (a -> low, b -> high)  [r2/r3-proven]
__device__ __forceinline__ unsigned pk2bf(float a, float b) {
    unsigned ua = __float_as_uint(a); ua = (ua + 0x7FFFu + ((ua >> 16) & 1u)) >> 16;
    unsigned ub = __float_as_uint(b); ub = (ub + 0x7FFFu + ((ub >> 16) & 1u)) & 0xFFFF0000u;
    return (ua & 0xFFFFu) | ub;
}

__device__ __forceinline__ f32x4 mfma16(i32x4 a, i32x4 b, f32x4 c) {
    return __builtin_amdgcn_mfma_f32_16x16x32_bf16(
        __builtin_bit_cast(bf16x8, a), __builtin_bit_cast(bf16x8, b), c, 0, 0, 0);
}

__device__ __forceinline__ float sig_fast(float v)  { return 1.0f / (1.0f + __expf(-v)); }
__device__ __forceinline__ float tanh_fast(float v) { return 1.0f - 2.0f / (1.0f + __expf(2.0f * v)); }

// ---------------------------------------------------------------------------
// K0: swizzle Wv,Wu (fp32 [512][128]) into bf16 FRAGMENT-LANE order (r2-proven)
// ---------------------------------------------------------------------------
__global__ void k0_prep(const float* __restrict__ Wv, const float* __restrict__ Wu,
                        unsigned short* __restrict__ Wp)
{
    int i = blockIdx.x * 256 + threadIdx.x;    // 0 .. 131071
    int g   = i >> 16;
    int rem = i & 65535;                       // kd*128 + n
    int kd  = rem >> 7;
    int n   = rem & 127;
    float w = g ? Wu[rem] : Wv[rem];
    unsigned u = __float_as_uint(w);
    u = (u + 0x7FFFu + ((u >> 16) & 1u)) >> 16;
    int kt = kd >> 5, lg = (kd >> 3) & 3, j = kd & 7, nt = n >> 4, lr = n & 15;
    Wp[kt * 8192 + g * 4096 + nt * 512 + lg * 128 + lr * 8 + j] = (unsigned short)u;
}

// ---------------------------------------------------------------------------
// K1 core (r8, verified): barrier-free MFMA mainloop. Also used as a probe
// template: MODE 0 = full, MODE 1 = loads-only, MODE 2 = compute-only.
// REPS repeats the whole block workload for rocprof visibility (>320us).
// ---------------------------------------------------------------------------
template<int MODE, int REPS>
__global__ __launch_bounds__(512, 1)
void k1_probe(const float* __restrict__ x, const unsigned short* __restrict__ Wp,
              const float* __restrict__ bv, const float* __restrict__ bu,
              const float* __restrict__ Wa, const float* __restrict__ ba,
              float* __restrict__ logits, float* __restrict__ vsink)
{
    __shared__ __align__(16) char lds[66560];  // buf0 32K | buf1 32K | sEp 1K

    const int t   = threadIdx.x;   // 0..511
    const int wid = t >> 6;        // 0..7
    const int l   = t & 63;
    const int lr  = l & 15;
    const int lg  = l >> 4;
    const int l7  = lr & 7;

    const int d = wid * 16 + lr;
    const float bvd = bv[d], bud = bu[d], wad = Wa[d];
    const float ba0 = ba[0];

    const int c     = t & 127;
    const int r0    = t >> 7;        // 0..3
    const int chalf = c & 1;
    const int clog  = c >> 1;        // 0..63

    const size_t blk_row0 = (size_t)blockIdx.x * 1024;
    const float* xblk = x + blk_row0 * LDIM;
    float* sEp = (float*)(lds + 65536);

    // ---- wave-resident weights (MODE 0/2) ----
    i32x4 Wreg[2][16];
    if constexpr (MODE != 1) {
        const unsigned short* wb = Wp + wid * 512 + l * 8;
#pragma unroll
        for (int kt = 0; kt < 16; ++kt) {
#pragma unroll
            for (int g = 0; g < 2; ++g)
                Wreg[g][kt] = *(const i32x4*)(wb + kt * 8192 + g * 4096);
        }
    }

    if constexpr (MODE == 1) {
        // ---- loads-only: same addresses, prefetch distance, barriers ----
        f32x4 facc = f32x4{0.f, 0.f, 0.f, 0.f};
        f32x4 xa[8], xb[8];
        for (int rep = 0; rep < REPS; ++rep) {
#pragma unroll
            for (int i = 0; i < 8; ++i)
                xa[i] = *(const f32x4*)(xblk + (size_t)(i * 4 + r0) * LDIM + c * 4);
#pragma unroll 2
            for (int j = 0; j < 32; ++j) {
                const bool even = !(j & 1);
                if (j < 31) {
                    const float* xt = xblk + (size_t)(j + 1) * 32 * LDIM;
#pragma unroll
                    for (int i = 0; i < 8; ++i) {
                        f32x4 v = *(const f32x4*)(xt + (size_t)(i * 4 + r0) * LDIM + c * 4);
                        if (even) xb[i] = v; else xa[i] = v;
                    }
                }
#pragma unroll
                for (int i = 0; i < 8; ++i) facc += even ? xa[i] : xb[i];
                __syncthreads();
                __syncthreads();
            }
        }
        vsink[blockIdx.x * 512 + t] = facc.x + facc.y + facc.z + facc.w;
        return;
    }

    f32x4 acc[2][2];
    f32x4 xg[8];

    if constexpr (MODE == 2) {
        // ---- compute-only: stage tile 0 once, then pure LDS+MFMA+epilogue ----
#pragma unroll
        for (int i = 0; i < 8; ++i)
            xg[i] = *(const f32x4*)(xblk + (size_t)(i * 4 + r0) * LDIM + c * 4);
#pragma unroll
        for (int i = 0; i < 8; ++i) {
            int row = i * 4 + r0;
            u32x2 wv; wv.x = pk2bf(xg[i].x, xg[i].y); wv.y = pk2bf(xg[i].z, xg[i].w);
            *(u32x2*)(lds + row * 1024 + ((clog ^ (row & 7)) * 16) + chalf * 8) = wv;
        }
        __syncthreads();
        for (int rep = 0; rep < REPS; ++rep) {
            for (int j = 0; j < 32; ++j) {
#pragma unroll
                for (int g = 0; g < 2; ++g)
#pragma unroll
                    for (int rt = 0; rt < 2; ++rt)
                        acc[g][rt] = f32x4{0.f, 0.f, 0.f, 0.f};
                const char* Xb = lds;   // always buf0
#pragma unroll
                for (int kt = 0; kt < 16; ++kt) {
                    i32x4 a0 = *(const i32x4*)(Xb + lr * 1024        + (((kt * 4 + lg) ^ l7) * 16));
                    i32x4 a1 = *(const i32x4*)(Xb + (16 + lr) * 1024 + (((kt * 4 + lg) ^ l7) * 16));
                    acc[0][0] = mfma16(a0, Wreg[0][kt], acc[0][0]);
                    acc[1][0] = mfma16(a0, Wreg[1][kt], acc[1][0]);
                    acc[0][1] = mfma16(a1, Wreg[0][kt], acc[0][1]);
                    acc[1][1] = mfma16(a1, Wreg[1][kt], acc[1][1]);
                }
#pragma unroll
                for (int rt = 0; rt < 2; ++rt) {
#pragma unroll
                    for (int ri = 0; ri < 4; ++ri) {
                        float vv = tanh_fast(acc[0][rt][ri] + bvd);
                        float uu = sig_fast (acc[1][rt][ri] + bud);
                        float s  = vv * uu * wad;
                        s += __shfl_xor(s, 1); s += __shfl_xor(s, 2);
                        s += __shfl_xor(s, 4); s += __shfl_xor(s, 8);
                        if (lr == 0) sEp[wid * 32 + rt * 16 + lg * 4 + ri] = s;
                    }
                }
                __syncthreads();
                if (t < 32) {
                    float s = ba0;
#pragma unroll
                    for (int w2 = 0; w2 < 8; ++w2) s += sEp[w2 * 32 + t];
                    logits[blk_row0 + j * 32 + t] = s;
                }
                __syncthreads();
            }
        }
        return;
    }

    // ---- MODE 0: full r8 pipeline, repeated REPS times ----
    for (int rep = 0; rep < REPS; ++rep) {
#pragma unroll
        for (int i = 0; i < 8; ++i)
            xg[i] = *(const f32x4*)(xblk + (size_t)(i * 4 + r0) * LDIM + c * 4);
#pragma unroll
        for (int i = 0; i < 8; ++i) {
            int row = i * 4 + r0;
            u32x2 wv; wv.x = pk2bf(xg[i].x, xg[i].y); wv.y = pk2bf(xg[i].z, xg[i].w);
            *(u32x2*)(lds + row * 1024 + ((clog ^ (row & 7)) * 16) + chalf * 8) = wv;
        }
        __syncthreads();

        int p = 0;
        for (int j = 0; j < 32; ++j) {
            const bool has_next = (j < 31);
            if (has_next) {
                const float* xt = xblk + (size_t)(j + 1) * 32 * LDIM;
#pragma unroll
                for (int i = 0; i < 8; ++i)
                    xg[i] = *(const f32x4*)(xt + (size_t)(i * 4 + r0) * LDIM + c * 4);
            }
#pragma unroll
            for (int g = 0; g < 2; ++g)
#pragma unroll
                for (int rt = 0; rt < 2; ++rt)
                    acc[g][rt] = f32x4{0.f, 0.f, 0.f, 0.f};
            const char* Xb = lds + p * 32768;
#pragma unroll
            for (int kt = 0; kt < 16; ++kt) {
                i32x4 a0 = *(const i32x4*)(Xb + lr * 1024        + (((kt * 4 + lg) ^ l7) * 16));
                i32x4 a1 = *(const i32x4*)(Xb + (16 + lr) * 1024 + (((kt * 4 + lg) ^ l7) * 16));
                acc[0][0] = mfma16(a0, Wreg[0][kt], acc[0][0]);
                acc[1][0] = mfma16(a0, Wreg[1][kt], acc[1][0]);
                acc[0][1] = mfma16(a1, Wreg[0][kt], acc[0][1]);
                acc[1][1] = mfma16(a1, Wreg[1][kt], acc[1][1]);
            }
            if (has_next) {
                char* Xw = lds + (p ^ 1) * 32768;
#pragma unroll
                for (int i = 0; i < 8; ++i) {
                    int row = i * 4 + r0;
                    u32x2 wv; wv.x = pk2bf(xg[i].x, xg[i].y); wv.y = pk2bf(xg[i].z, xg[i].w);
                    *(u32x2*)(Xw + row * 1024 + ((clog ^ (row & 7)) * 16) + chalf * 8) = wv;
                }
            }
#pragma unroll
            for (int rt = 0; rt < 2; ++rt) {
#pragma unroll
                for (int ri = 0; ri < 4; ++ri) {
                    float vv = tanh_fast(acc[0][rt][ri] + bvd);
                    float uu = sig_fast (acc[1][rt][ri] + bud);
                    float s  = vv * uu * wad;
                    s += __shfl_xor(s, 1); s += __shfl_xor(s, 2);
                    s += __shfl_xor(s, 4); s += __shfl_xor(s, 8);
                    if (lr == 0) sEp[wid * 32 + rt * 16 + lg * 4 + ri] = s;
                }
            }
            __syncthreads();
            if (t < 32) {
                float s = ba0;
#pragma unroll
                for (int w2 = 0; w2 < 8; ++w2) s += sEp[w2 * 32 + t];
                logits[blk_row0 + j * 32 + t] = s;
            }
            __syncthreads();
            p ^= 1;
        }
    }
}

// ---------------------------------------------------------------------------
// K3a: fused band-classify + softmax (verbatim, verified).
// ---------------------------------------------------------------------------
__global__ void k3a_band_softmax(float* __restrict__ A, const float* __restrict__ mask,
                                 const int* __restrict__ kp, int* __restrict__ idxWS,
                                 int* __restrict__ candIdx, int* __restrict__ counts)
{
    __shared__ float sredf[4];
    __shared__ int sredi[4];
    __shared__ int sIn, sCand;
    const int b = blockIdx.x;
    const int t = threadIdx.x;
    const int w = t >> 6;
    int k = get_k(kp); if (k > KCAP) k = KCAP;
    float* Ab = A + (size_t)b * NN;
    const float* mb = mask + (size_t)b * NN;

    float raw[64]; u64 mbits = 0ULL;
#pragma unroll
    for (int j = 0; j < 64; ++j) {
        int i = t + j * 256;
        raw[j] = Ab[i];
        if (mb[i] > 0.0f) mbits |= (1ULL << j);
    }
    unsigned kk[64];
#pragma unroll
    for (int j = 0; j < 64; ++j) {
        float v = ((mbits >> j) & 1) ? raw[j] : -3.0e38f;
        kk[j] = okey(v);
    }
    unsigned lo = 0u, hi = 0xFFFFFFFFu;
    while (lo < hi) {
        unsigned span = hi - lo;
        unsigned mid = lo + (span >> 1) + (span & 1u);
        int c = 0;
#pragma unroll
        for (int j = 0; j < 64; ++j) c += (kk[j] >= mid) ? 1 : 0;
#pragma unroll
        for (int m2 = 1; m2 < 64; m2 <<= 1) c += __shfl_xor(c, m2);
        __syncthreads();
        if ((t & 63) == 0) sredi[w] = c;
        __syncthreads();
        c = sredi[0] + sredi[1] + sredi[2] + sredi[3];
        if (c >= k) lo = mid; else hi = mid - 1;
    }
    const float tv = inv_okey(lo);

    if (t == 0) { sIn = 0; sCand = 0; }
    __syncthreads();
    const float hiB = tv + DELTA, loB = tv - DELTA;
#pragma unroll
    for (int j = 0; j < 64; ++j) {
        int i = t + j * 256;
        float v = ((mbits >> j) & 1) ? raw[j] : -3.0e38f;
        if (v > hiB)       { int p = atomicAdd(&sIn, 1);   if (p < KCAP) idxWS[b * KCAP + p] = i; }
        else if (v >= loB) { int p = atomicAdd(&sCand, 1); if (p < CCAP) candIdx[b * CCAP + p] = i; }
    }

    float mx = -INFINITY;
#pragma unroll
    for (int j = 0; j < 64; ++j) mx = fmaxf(mx, raw[j]);
#pragma unroll
    for (int m2 = 1; m2 < 64; m2 <<= 1) mx = fmaxf(mx, __shfl_xor(mx, m2));
    __syncthreads();
    if ((t & 63) == 0) sredf[w] = mx;
    __syncthreads();
    mx = fmaxf(fmaxf(sredf[0], sredf[1]), fmaxf(sredf[2], sredf[3]));

    float sAll = 0.f, sM = 0.f;
#pragma unroll
    for (int j = 0; j < 64; ++j) {
        float e = __expf(raw[j] - mx);
        sAll += e;
        if ((mbits >> j) & 1) sM += e;
    }
#pragma unroll
    for (int m2 = 1; m2 < 64; m2 <<= 1) sAll += __shfl_xor(sAll, m2);
    __syncthreads();
    if ((t & 63) == 0) sredf[w] = sAll;
    __syncthreads();
    sAll = sredf[0] + sredf[1] + sredf[2] + sredf[3];
#pragma unroll
    for (int m2 = 1; m2 < 64; m2 <<= 1) sM += __shfl_xor(sM, m2);
    __syncthreads();
    if ((t & 63) == 0) sredf[w] = sM;
    __syncthreads();
    sM = sredf[0] + sredf[1] + sredf[2] + sredf[3];

    const float inv = 1.0f / (sM + EPSV * sAll);
#pragma unroll
    for (int j = 0; j < 64; ++j) {
        int i = t + j * 256;
        float e = __expf(raw[j] - mx);
        Ab[i] = ((mbits >> j) & 1) ? e * inv : 0.0f;
    }
    if (t == 0) {
        int m1 = sIn;   if (m1 > k)    m1 = k;
        int cc = sCand; if (cc > CCAP) cc = CCAP;
        counts[b * 4]     = m1;
        counts[b * 4 + 1] = cc;
    }
}

// ---------------------------------------------------------------------------
// K3b: exact fp32 logits for band candidates, row-batched (verbatim).
// ---------------------------------------------------------------------------
__global__ void k3b_exact(const float* __restrict__ x,
                          const float* __restrict__ Wv, const float* __restrict__ bv,
                          const float* __restrict__ Wu, const float* __restrict__ bu,
                          const float* __restrict__ Wa, const float* __restrict__ ba,
                          const int* __restrict__ candIdx, const int* __restrict__ counts,
                          float* __restrict__ candVal)
{
    __shared__ __align__(16) float sx[ROWB][LDIM];   // 16 KB
    __shared__ float sred[2][ROWB];
    const int b = blockIdx.x;
    const int t = threadIdx.x;          // 0..127
    const int w = t >> 6;
    const int cnt = counts[b * 4 + 1];
    const float bvt = bv[t], but = bu[t], wat = Wa[t], ba0 = ba[0];

    for (int base = blockIdx.y * ROWB; base < cnt; base += gridDim.y * ROWB) {
        const int nr = min(ROWB, cnt - base);
        for (int r = 0; r < nr; ++r) {
            const int row = candIdx[b * CCAP + base + r];
            ((f32x4*)&sx[r][0])[t] =
                ((const f32x4*)(x + ((size_t)b * NN + (size_t)row) * LDIM))[t];
        }
        __syncthreads();

        float dv[ROWB], du[ROWB];
#pragma unroll
        for (int r = 0; r < ROWB; ++r) { dv[r] = bvt; du[r] = but; }
#pragma unroll 4
        for (int ll = 0; ll < LDIM; ++ll) {
            const float wvl = Wv[ll * DDIM + t];
            const float wul = Wu[ll * DDIM + t];
#pragma unroll
            for (int r = 0; r < ROWB; ++r) {
                const float xv = sx[r][ll];
                dv[r] = fmaf(xv, wvl, dv[r]);
                du[r] = fmaf(xv, wul, du[r]);
            }
        }
#pragma unroll
        for (int r = 0; r < ROWB; ++r) {
            float c = tanhf(dv[r]) * (1.0f / (1.0f + expf(-du[r]))) * wat;
            c += __shfl_xor(c, 1);  c += __shfl_xor(c, 2);
            c += __shfl_xor(c, 4);  c += __shfl_xor(c, 8);
            c += __shfl_xor(c, 16); c += __shfl_xor(c, 32);
            if ((t & 63) == 0) sred[w][r] = c;
        }
        __syncthreads();
        if (t < nr) candVal[b * CCAP + base + t] = sred[0][t] + sred[1][t] + ba0;
        __syncthreads();
    }
}

// ---------------------------------------------------------------------------
// K34: select + rank-sort + gather + mean-pool + MLP + argmax (verbatim).
// ---------------------------------------------------------------------------
__global__ void k34_select_final(const float* __restrict__ x, const int* __restrict__ kp,
                                 const int* __restrict__ candIdx, const float* __restrict__ candVal,
                                 const int* __restrict__ counts, const int* __restrict__ idxWS,
                                 const float* __restrict__ W1, const float* __restrict__ b1,
                                 const float* __restrict__ W2, const float* __restrict__ b2,
                                 float* __restrict__ Yprob, float* __restrict__ Yhat)
{
    __shared__ u64 keys[CCAP];
    __shared__ int sIdx[KCAP];
    __shared__ int sFinal[KCAP];
    __shared__ int sPos;
    __shared__ float sPooled[LDIM];
    __shared__ float sH[HIDD];
    __shared__ float sY[4];
    const int b = blockIdx.x;
    const int t = threadIdx.x;
    int k = get_k(kp); if (k > KCAP) k = KCAP;
    const int m1  = counts[b * 4];
    const int cnt = counts[b * 4 + 1];
    int need = k - m1; if (need < 0) need = 0; if (need > cnt) need = cnt;

    for (int i = t; i < cnt; i += 256)
        keys[i] = (((u64)okey(candVal[b * CCAP + i])) << 14)
                | (u64)(16383 - candIdx[b * CCAP + i]);
    if (t < m1) sIdx[t] = idxWS[b * KCAP + t];
    if (t == 0) sPos = 0;
    if (t < KCAP) sFinal[t] = 0;
    __syncthreads();
    for (int i = t; i < cnt; i += 256) {
        u64 mk = keys[i];
        int rank = 0;
        for (int j = 0; j < cnt; ++j) rank += (keys[j] > mk) ? 1 : 0;
        if (rank < need) { int p = atomicAdd(&sPos, 1); sIdx[m1 + p] = candIdx[b * CCAP + i]; }
    }
    __syncthreads();
    int tot = m1 + need; if (tot > k) tot = k;
    if (t < tot) {
        int myv = sIdx[t];
        int rank = 0;
        for (int e = 0; e < tot; ++e) rank += (sIdx[e] < myv) ? 1 : 0;
        sFinal[rank] = myv;
    }
    __syncthreads();

    float a0 = 0.0f, a1 = 0.0f;
    for (int j = 0; j < k; ++j) {
        const float* xr = x + ((size_t)b * NN + (size_t)sFinal[j]) * LDIM;
        a0 += xr[t];
        a1 += xr[t + 256];
    }
    const float invk = 1.0f / (float)k;
    sPooled[t]       = a0 * invk;
    sPooled[t + 256] = a1 * invk;
    __syncthreads();

    if (t < HIDD) {
        float acc = b1[t];
        for (int ll = 0; ll < LDIM; ++ll) acc = fmaf(sPooled[ll], W1[ll * HIDD + t], acc);
        sH[t] = fmaxf(acc, 0.0f);
    }
    __syncthreads();
    if (t < NCLS) {
        float y = b2[t];
        for (int hh = 0; hh < HIDD; ++hh) y = fmaf(sH[hh], W2[hh * NCLS + t], y);
        Yprob[b * NCLS + t] = y;
        sY[t] = y;
    }
    __syncthreads();
    if (t == 0) {
        int am = 0; float bst = sY[0];
        if (sY[1] > bst) { bst = sY[1]; am = 1; }
        if (sY[2] > bst) { bst = sY[2]; am = 2; }
        Yhat[b] = (float)am;
    }
}

// ---------------------------------------------------------------------------
extern "C" void kernel_launch(void* const* d_in, const int* in_sizes, int n_in,
                              void* d_out, int out_size, void* d_ws, size_t ws_size,
                              hipStream_t stream)
{
    const float* x    = (const float*)d_in[0];
    const float* mask = (const float*)d_in[1];
    const float* Wv   = (const float*)d_in[2];
    const float* bv   = (const float*)d_in[3];
    const float* Wu   = (const float*)d_in[4];
    const float* bu   = (const float*)d_in[5];
    const float* Wa   = (const float*)d_in[6];
    const float* ba   = (const float*)d_in[7];
    const float* W1   = (const float*)d_in[8];
    const float* b1   = (const float*)d_in[9];
    const float* W2   = (const float*)d_in[10];
    const float* b2   = (const float*)d_in[11];
    const int*   kp   = (const int*)d_in[12];

    float* out   = (float*)d_out;
    float* Yprob = out;        // [16,3] = 48
    float* Yhat  = out + 48;   // [16]
    float* A     = out + 64;   // [16,16384]

    char* wsb = (char*)d_ws;
    unsigned short* Wp = (unsigned short*)wsb;        // 262144 B
    int*   idxWS   = (int*)  (wsb + 262144);          // 16 KB
    int*   candIdx = (int*)  (wsb + 278528);          // 64 KB
    float* candVal = (float*)(wsb + 344064);          // 64 KB
    int*   counts  = (int*)  (wsb + 409600);          // 256 B
    float* vsink   = (float*)(wsb + 1048576);         // 512 KB  (probe sink)
    float* Ascr    = (float*)(wsb + 2097152);         // 1 MB    (probe logits)

    // ---- real pipeline (r8, passing) ----
    k0_prep  <<<512, 256, 0, stream>>>(Wv, Wu, Wp);
    k1_probe<0, 1><<<256, 512, 0, stream>>>(x, Wp, bv, bu, Wa, ba, A, vsink);
    k3a_band_softmax<<<NB, 256, 0, stream>>>(A, mask, kp, idxWS, candIdx, counts);
    k3b_exact<<<dim3(NB, 32), 128, 0, stream>>>(x, Wv, bv, Wu, bu, Wa, ba,
                                                candIdx, counts, candVal);
    k34_select_final<<<NB, 256, 0, stream>>>(x, kp, candIdx, candVal, counts, idxWS,
                                             W1, b1, W2, b2, Yprob, Yhat);

    // ---- diagnostic probes (write scratch only; repeated for rocprof
    //      visibility above the 2.1GB fillBuffer dispatches ~320us) ----
    k1_probe<0, 3><<<256, 512, 0, stream>>>(x, Wp, bv, bu, Wa, ba, Ascr, vsink);  // V1 full x3
    k1_probe<1, 6><<<256, 512, 0, stream>>>(x, Wp, bv, bu, Wa, ba, Ascr, vsink);  // V2 loads x6
    k1_probe<2, 10><<<256, 512, 0, stream>>>(x, Wp, bv, bu, Wa, ba, Ascr, vsink); // V3 compute x10
}

// Round 10
// 626.813 us; speedup vs baseline: 3.6406x; 3.6406x over previous
//
#include <hip/hip_runtime.h>
#include <math.h>

#define NB   16
#define NN   16384
#define LDIM 512
#define DDIM 128
#define HIDD 128
#define NCLS 3
#define KCAP 256
#define CC2  512
#define EPSV 1e-8f
#define DELTA 0.02f

typedef float  f32x4  __attribute__((ext_vector_type(4)));
typedef int    i32x4  __attribute__((ext_vector_type(4)));
typedef unsigned u32x2 __attribute__((ext_vector_type(2)));
typedef __bf16 bf16x8 __attribute__((ext_vector_type(8)));
typedef unsigned long long u64;

__device__ __forceinline__ int get_k(const int* kp) {
    int k = kp[0];
    if (k < 1 || k > NN) {
        float f = __int_as_float(k);
        if (f >= 1.0f && f <= (float)NN) k = (int)f;
        else k = 70;
    }
    if (k > NN) k = NN;
    return k;
}

__device__ __forceinline__ unsigned okey(float f) {
    unsigned u = __float_as_uint(f);
    return (u & 0x80000000u) ? ~u : (u | 0x80000000u);
}
__device__ __forceinline__ float inv_okey(unsigned k) {
    unsigned u = (k & 0x80000000u) ? (k & 0x7FFFFFFFu) : ~k;
    return __uint_as_float(u);
}

// pack two fp32 -> two RNE bf16 in one u32 (a -> low, b -> high)  [r2/r3-proven]
__device__ __forceinline__ unsigned pk2bf(float a, float b) {
    unsigned ua = __float_as_uint(a); ua = (ua + 0x7FFFu + ((ua >> 16) & 1u)) >> 16;
    unsigned ub = __float_as_uint(b); ub = (ub + 0x7FFFu + ((ub >> 16) & 1u)) & 0xFFFF0000u;
    return (ua & 0xFFFFu) | ub;
}

__device__ __forceinline__ f32x4 mfma16(i32x4 a, i32x4 b, f32x4 c) {
    return __builtin_amdgcn_mfma_f32_16x16x32_bf16(
        __builtin_bit_cast(bf16x8, a), __builtin_bit_cast(bf16x8, b), c, 0, 0, 0);
}

__device__ __forceinline__ float sig_fast(float v)  { return 1.0f / (1.0f + __expf(-v)); }
__device__ __forceinline__ float tanh_fast(float v) { return 1.0f - 2.0f / (1.0f + __expf(2.0f * v)); }

// ---------------------------------------------------------------------------
// K0: swizzle Wv,Wu (fp32 [512][128]) into bf16 FRAGMENT-LANE order (r2-proven):
// short-idx = kt*8192 + g*4096 + nt*512 + lane*8 + j, lane = lg*16 + lr
//   (kt=k/32, lg=(k/8)%4, j=k%8, nt=n/16, lr=n%16).
// By MFMA A/B layout symmetry this serves as the A-operand (W as A): lane l
// supplies A[row=l&15 <-> d][k=(l>>4)*8+j] = W[k][nt*16+(l&15)].
// ---------------------------------------------------------------------------
__global__ void k0_prep(const float* __restrict__ Wv, const float* __restrict__ Wu,
                        unsigned short* __restrict__ Wp)
{
    int i = blockIdx.x * 256 + threadIdx.x;    // 0 .. 131071
    int g   = i >> 16;
    int rem = i & 65535;                       // kd*128 + n
    int kd  = rem >> 7;
    int n   = rem & 127;
    float w = g ? Wu[rem] : Wv[rem];
    unsigned u = __float_as_uint(w);
    u = (u + 0x7FFFu + ((u >> 16) & 1u)) >> 16;
    int kt = kd >> 5, lg = (kd >> 3) & 3, j = kd & 7, nt = n >> 4, lr = n & 15;
    Wp[kt * 8192 + g * 4096 + nt * 512 + lg * 128 + lr * 8 + j] = (unsigned short)u;
}

// ---------------------------------------------------------------------------
// K1 (r10): r8 pipeline with OPERAND-SWAPPED MFMA: acc = mfma(W, x, acc).
// D: row = d_local = (l>>4)*4+reg, col = x-row = l&15  -> the d-reduction is
// 4 in-lane regs (VALU) + 2 shfl_xor, vs r8's 32 shfl + 8 LDS writes per
// wave per j-tile (8x fewer DS epilogue ops). Staging, LDS layout, Wreg,
// barriers all verbatim r8 (numerically verified there).
// ---------------------------------------------------------------------------
__global__ __launch_bounds__(512, 1)
void k1_mfma(const float* __restrict__ x, const unsigned short* __restrict__ Wp,
             const float* __restrict__ bv, const float* __restrict__ bu,
             const float* __restrict__ Wa, const float* __restrict__ ba,
             float* __restrict__ logits)
{
    __shared__ __align__(16) char lds[66560];  // buf0 32K | buf1 32K | sEp 1K

    const int t   = threadIdx.x;   // 0..511
    const int wid = t >> 6;        // 0..7
    const int l   = t & 63;
    const int lr  = l & 15;
    const int lg  = l >> 4;
    const int l7  = lr & 7;

    // ---- wave-resident weights: A-frag (g, nt=wid, kt) at lane l ----
    i32x4 Wreg[2][16];
    {
        const unsigned short* wb = Wp + wid * 512 + l * 8;
#pragma unroll
        for (int kt = 0; kt < 16; ++kt) {
#pragma unroll
            for (int g = 0; g < 2; ++g)
                Wreg[g][kt] = *(const i32x4*)(wb + kt * 8192 + g * 4096);
        }
    }

    // epilogue constants: lane's 4 d-rows = wid*16 + lg*4 + r
    const int dbase = wid * 16 + lg * 4;
    float bvR[4], buR[4], waR[4];
#pragma unroll
    for (int r = 0; r < 4; ++r) {
        bvR[r] = bv[dbase + r]; buR[r] = bu[dbase + r]; waR[r] = Wa[dbase + r];
    }
    const float ba0 = ba[0];

    // staging role: thread t handles 16B-chunk c=t&127 of rows r0, r0+4, ...
    const int c     = t & 127;
    const int r0    = t >> 7;        // 0..3
    const int chalf = c & 1;
    const int clog  = c >> 1;        // 0..63 (16B chunk within row)

    const size_t blk_row0 = (size_t)blockIdx.x * 1024;
    const float* xblk = x + blk_row0 * LDIM;
    float* sEp = (float*)(lds + 65536);   // [8 waves][32 rows]

    f32x4 acc[2][2];
    f32x4 xg[8];

    // ---- prologue: stage tile 0 into buf0 ----
#pragma unroll
    for (int i = 0; i < 8; ++i)
        xg[i] = *(const f32x4*)(xblk + (size_t)(i * 4 + r0) * LDIM + c * 4);
#pragma unroll
    for (int i = 0; i < 8; ++i) {
        int row = i * 4 + r0;
        u32x2 wv; wv.x = pk2bf(xg[i].x, xg[i].y); wv.y = pk2bf(xg[i].z, xg[i].w);
        *(u32x2*)(lds + row * 1024 + ((clog ^ (row & 7)) * 16) + chalf * 8) = wv;
    }
    __syncthreads();

    int p = 0;
    for (int j = 0; j < 32; ++j) {
        const bool has_next = (j < 31);
        // (1) issue tile j+1 global loads (latency hides under mainloop)
        if (has_next) {
            const float* xt = xblk + (size_t)(j + 1) * 32 * LDIM;
#pragma unroll
            for (int i = 0; i < 8; ++i)
                xg[i] = *(const f32x4*)(xt + (size_t)(i * 4 + r0) * LDIM + c * 4);
        }
        // (2) barrier-free mainloop over full K (B = x frags from LDS)
#pragma unroll
        for (int g = 0; g < 2; ++g)
#pragma unroll
            for (int rf = 0; rf < 2; ++rf)
                acc[g][rf] = f32x4{0.f, 0.f, 0.f, 0.f};
        const char* Xb = lds + p * 32768;
#pragma unroll
        for (int kt = 0; kt < 16; ++kt) {
            i32x4 b0 = *(const i32x4*)(Xb + lr * 1024        + (((kt * 4 + lg) ^ l7) * 16));
            i32x4 b1 = *(const i32x4*)(Xb + (16 + lr) * 1024 + (((kt * 4 + lg) ^ l7) * 16));
            acc[0][0] = mfma16(Wreg[0][kt], b0, acc[0][0]);
            acc[1][0] = mfma16(Wreg[1][kt], b0, acc[1][0]);
            acc[0][1] = mfma16(Wreg[0][kt], b1, acc[0][1]);
            acc[1][1] = mfma16(Wreg[1][kt], b1, acc[1][1]);
        }
        // (3) pack + write tile j+1 into the other buffer
        if (has_next) {
            char* Xw = lds + (p ^ 1) * 32768;
#pragma unroll
            for (int i = 0; i < 8; ++i) {
                int row = i * 4 + r0;
                u32x2 wv; wv.x = pk2bf(xg[i].x, xg[i].y); wv.y = pk2bf(xg[i].z, xg[i].w);
                *(u32x2*)(Xw + row * 1024 + ((clog ^ (row & 7)) * 16) + chalf * 8) = wv;
            }
        }
        // (4) epilogue: d lives in regs -> 4-term in-lane sum + 2 shfl per rf
#pragma unroll
        for (int rf = 0; rf < 2; ++rf) {
            float s = 0.f;
#pragma unroll
            for (int r = 0; r < 4; ++r) {
                float vv = tanh_fast(acc[0][rf][r] + bvR[r]);
                float uu = sig_fast (acc[1][rf][r] + buR[r]);
                s = fmaf(vv * uu, waR[r], s);
            }
            s += __shfl_xor(s, 16);
            s += __shfl_xor(s, 32);
            if (l < 16) sEp[wid * 32 + rf * 16 + l] = s;
        }
        __syncthreads();
        if (t < 32) {
            float s = ba0;
#pragma unroll
            for (int w2 = 0; w2 < 8; ++w2) s += sEp[w2 * 32 + t];
            logits[blk_row0 + j * 32 + t] = s;
        }
        __syncthreads();   // protects sEp reuse + publishes buf p^1
        p ^= 1;
    }
}

// ---------------------------------------------------------------------------
// K3 fused: band-classify + softmax + exact recompute + select + pool + MLP.
// One block per batch (16 blocks). Candidate data stays in LDS.
// ---------------------------------------------------------------------------
__global__ void k3_fused(float* __restrict__ A, const float* __restrict__ mask,
                         const float* __restrict__ x, const int* __restrict__ kp,
                         const float* __restrict__ Wv, const float* __restrict__ bv,
                         const float* __restrict__ Wu, const float* __restrict__ bu,
                         const float* __restrict__ Wa, const float* __restrict__ ba,
                         const float* __restrict__ W1, const float* __restrict__ b1,
                         const float* __restrict__ W2, const float* __restrict__ b2,
                         float* __restrict__ Yprob, float* __restrict__ Yhat)
{
    __shared__ float sredf[8];
    __shared__ int sredi[4];
    __shared__ int sIn, sCand, sPos;
    __shared__ int sInIdx[KCAP];                   // definite-in
    __shared__ int sCandIdx[CC2];
    __shared__ float sCandVal[CC2];
    __shared__ __align__(16) float sx2[2][LDIM];   // 4KB row stage
    __shared__ u64 keys[CC2];
    __shared__ int sIdx[KCAP];
    __shared__ int sFinal[KCAP];
    __shared__ float sPooled[LDIM];
    __shared__ float sH[HIDD];
    __shared__ float sY[4];

    const int b = blockIdx.x;
    const int t = threadIdx.x;
    const int w = t >> 6;
    int k = get_k(kp); if (k > KCAP) k = KCAP;
    float* Ab = A + (size_t)b * NN;
    const float* mb = mask + (size_t)b * NN;

    // ================= Phase 1: band classify + softmax (r3-proven body) ====
    float raw[64]; u64 mbits = 0ULL;
#pragma unroll
    for (int j = 0; j < 64; ++j) {
        int i = t + j * 256;
        raw[j] = Ab[i];
        if (mb[i] > 0.0f) mbits |= (1ULL << j);
    }
    unsigned kk[64];
#pragma unroll
    for (int j = 0; j < 64; ++j) {
        float v = ((mbits >> j) & 1) ? raw[j] : -3.0e38f;
        kk[j] = okey(v);
    }
    unsigned lo = 0u, hi = 0xFFFFFFFFu;
    while (lo < hi) {
        unsigned span = hi - lo;
        unsigned mid = lo + (span >> 1) + (span & 1u);
        int c = 0;
#pragma unroll
        for (int j = 0; j < 64; ++j) c += (kk[j] >= mid) ? 1 : 0;
#pragma unroll
        for (int m2 = 1; m2 < 64; m2 <<= 1) c += __shfl_xor(c, m2);
        __syncthreads();
        if ((t & 63) == 0) sredi[w] = c;
        __syncthreads();
        c = sredi[0] + sredi[1] + sredi[2] + sredi[3];
        if (c >= k) lo = mid; else hi = mid - 1;
    }
    const float tv = inv_okey(lo);

    if (t == 0) { sIn = 0; sCand = 0; }
    __syncthreads();
    const float hiB = tv + DELTA, loB = tv - DELTA;
#pragma unroll
    for (int j = 0; j < 64; ++j) {
        int i = t + j * 256;
        float v = ((mbits >> j) & 1) ? raw[j] : -3.0e38f;
        if (v > hiB)       { int p = atomicAdd(&sIn, 1);   if (p < KCAP) sInIdx[p]   = i; }
        else if (v >= loB) { int p = atomicAdd(&sCand, 1); if (p < CC2)  sCandIdx[p] = i; }
    }

    float mx = -INFINITY;
#pragma unroll
    for (int j = 0; j < 64; ++j) mx = fmaxf(mx, raw[j]);
#pragma unroll
    for (int m2 = 1; m2 < 64; m2 <<= 1) mx = fmaxf(mx, __shfl_xor(mx, m2));
    __syncthreads();
    if ((t & 63) == 0) sredf[w] = mx;
    __syncthreads();
    mx = fmaxf(fmaxf(sredf[0], sredf[1]), fmaxf(sredf[2], sredf[3]));

    float sAll = 0.f, sM = 0.f;
#pragma unroll
    for (int j = 0; j < 64; ++j) {
        float e = __expf(raw[j] - mx);
        sAll += e;
        if ((mbits >> j) & 1) sM += e;
    }
#pragma unroll
    for (int m2 = 1; m2 < 64; m2 <<= 1) sAll += __shfl_xor(sAll, m2);
    __syncthreads();
    if ((t & 63) == 0) sredf[w] = sAll;
    __syncthreads();
    sAll = sredf[0] + sredf[1] + sredf[2] + sredf[3];
#pragma unroll
    for (int m2 = 1; m2 < 64; m2 <<= 1) sM += __shfl_xor(sM, m2);
    __syncthreads();
    if ((t & 63) == 0) sredf[w] = sM;
    __syncthreads();
    sM = sredf[0] + sredf[1] + sredf[2] + sredf[3];

    const float inv = 1.0f / (sM + EPSV * sAll);
#pragma unroll
    for (int j = 0; j < 64; ++j) {
        int i = t + j * 256;
        float e = __expf(raw[j] - mx);
        Ab[i] = ((mbits >> j) & 1) ? e * inv : 0.0f;
    }
    __syncthreads();
    int m1  = sIn;   if (m1 > k)   m1 = k;
    int cnt = sCand; if (cnt > CC2) cnt = CC2;

    // ================= Phase 2: exact fp32 logits for candidates ============
    // 2 candidates per round: thread t -> cand ci=t>>7, d-col t&127.
    {
        const int ci = t >> 7;        // 0/1
        const int d  = t & 127;
        const float bvt = bv[d], but = bu[d], wat = Wa[d], ba0 = ba[0];
        for (int base = 0; base < cnt; base += 2) {
            const int nr = min(2, cnt - base);
            const int rowi = (ci < nr) ? (base + ci) : base;
            const int row = sCandIdx[rowi];
            ((f32x4*)&sx2[0][0])[t] =
                ((const f32x4*)(x + ((size_t)b * NN + (size_t)row) * LDIM))[t & 127];
            __syncthreads();
            float dv = bvt, du = but;
#pragma unroll 4
            for (int ll = 0; ll < LDIM; ++ll) {
                const float xv = sx2[ci][ll];
                dv = fmaf(xv, Wv[ll * DDIM + d], dv);
                du = fmaf(xv, Wu[ll * DDIM + d], du);
            }
            float cc = tanhf(dv) * (1.0f / (1.0f + expf(-du))) * wat;
#pragma unroll
            for (int m2 = 1; m2 < 64; m2 <<= 1) cc += __shfl_xor(cc, m2);
            if ((t & 63) == 0) sredf[w] = cc;      // wave partials
            __syncthreads();
            if (t == 0 && nr > 0) sCandVal[base]     = sredf[0] + sredf[1] + ba0;
            if (t == 1 && nr > 1) sCandVal[base + 1] = sredf[2] + sredf[3] + ba0;
            __syncthreads();
        }
    }

    // ================= Phase 3: select + rank-sort + pool + MLP =============
    int need = k - m1; if (need < 0) need = 0; if (need > cnt) need = cnt;

    for (int i = t; i < cnt; i += 256)
        keys[i] = (((u64)okey(sCandVal[i])) << 14) | (u64)(16383 - sCandIdx[i]);
    if (t < m1) sIdx[t] = sInIdx[t];
    if (t == 0) sPos = 0;
    if (t < KCAP) sFinal[t] = 0;
    __syncthreads();
    for (int i = t; i < cnt; i += 256) {
        u64 mk = keys[i];
        int rank = 0;
        for (int j = 0; j < cnt; ++j) rank += (keys[j] > mk) ? 1 : 0;
        if (rank < need) { int p = atomicAdd(&sPos, 1); sIdx[m1 + p] = sCandIdx[i]; }
    }
    __syncthreads();
    int tot = m1 + need; if (tot > k) tot = k;
    if (t < tot) {
        int myv = sIdx[t];
        int rank = 0;
        for (int e = 0; e < tot; ++e) rank += (sIdx[e] < myv) ? 1 : 0;
        sFinal[rank] = myv;
    }
    __syncthreads();

    // mean-pool top-k rows (8-wide unrolled independent loads for ILP)
    float a0 = 0.0f, a1 = 0.0f;
    {
        int j = 0;
        for (; j + 8 <= k; j += 8) {
            float t0[8], t1[8];
#pragma unroll
            for (int u2 = 0; u2 < 8; ++u2) {
                const float* xr = x + ((size_t)b * NN + (size_t)sFinal[j + u2]) * LDIM;
                t0[u2] = xr[t]; t1[u2] = xr[t + 256];
            }
#pragma unroll
            for (int u2 = 0; u2 < 8; ++u2) { a0 += t0[u2]; a1 += t1[u2]; }
        }
        for (; j < k; ++j) {
            const float* xr = x + ((size_t)b * NN + (size_t)sFinal[j]) * LDIM;
            a0 += xr[t]; a1 += xr[t + 256];
        }
    }
    const float invk = 1.0f / (float)k;
    sPooled[t]       = a0 * invk;
    sPooled[t + 256] = a1 * invk;
    __syncthreads();

    if (t < HIDD) {
        float acc = b1[t];
        for (int ll = 0; ll < LDIM; ++ll) acc = fmaf(sPooled[ll], W1[ll * HIDD + t], acc);
        sH[t] = fmaxf(acc, 0.0f);
    }
    __syncthreads();
    if (t < NCLS) {
        float y = b2[t];
        for (int hh = 0; hh < HIDD; ++hh) y = fmaf(sH[hh], W2[hh * NCLS + t], y);
        Yprob[b * NCLS + t] = y;
        sY[t] = y;
    }
    __syncthreads();
    if (t == 0) {
        int am = 0; float bst = sY[0];
        if (sY[1] > bst) { bst = sY[1]; am = 1; }
        if (sY[2] > bst) { bst = sY[2]; am = 2; }
        Yhat[b] = (float)am;
    }
}

// ---------------------------------------------------------------------------
extern "C" void kernel_launch(void* const* d_in, const int* in_sizes, int n_in,
                              void* d_out, int out_size, void* d_ws, size_t ws_size,
                              hipStream_t stream)
{
    const float* x    = (const float*)d_in[0];
    const float* mask = (const float*)d_in[1];
    const float* Wv   = (const float*)d_in[2];
    const float* bv   = (const float*)d_in[3];
    const float* Wu   = (const float*)d_in[4];
    const float* bu   = (const float*)d_in[5];
    const float* Wa   = (const float*)d_in[6];
    const float* ba   = (const float*)d_in[7];
    const float* W1   = (const float*)d_in[8];
    const float* b1   = (const float*)d_in[9];
    const float* W2   = (const float*)d_in[10];
    const float* b2   = (const float*)d_in[11];
    const int*   kp   = (const int*)d_in[12];

    float* out   = (float*)d_out;
    float* Yprob = out;        // [16,3] = 48
    float* Yhat  = out + 48;   // [16]
    float* A     = out + 64;   // [16,16384]  (logits first, softmax in-place)

    unsigned short* Wp = (unsigned short*)d_ws;       // 262144 B

    k0_prep <<<512, 256, 0, stream>>>(Wv, Wu, Wp);
    k1_mfma <<<256, 512, 0, stream>>>(x, Wp, bv, bu, Wa, ba, A);
    k3_fused<<<NB, 256, 0, stream>>>(A, mask, x, kp, Wv, bv, Wu, bu, Wa, ba,
                                     W1, b1, W2, b2, Yprob, Yhat);
}

// Round 11
// 257.327 us; speedup vs baseline: 8.8680x; 2.4359x over previous
//
#include <hip/hip_runtime.h>
#include <math.h>

#define NB   16
#define NN   16384
#define LDIM 512
#define DDIM 128
#define HIDD 128
#define NCLS 3
#define KCAP 256
#define CCAP 1024
#define ROWB 8
#define EPSV 1e-8f
#define DELTA 0.02f

typedef float  f32x4  __attribute__((ext_vector_type(4)));
typedef int    i32x4  __attribute__((ext_vector_type(4)));
typedef unsigned u32x2 __attribute__((ext_vector_type(2)));
typedef __bf16 bf16x8 __attribute__((ext_vector_type(8)));
typedef unsigned long long u64;

__device__ __forceinline__ int get_k(const int* kp) {
    int k = kp[0];
    if (k < 1 || k > NN) {
        float f = __int_as_float(k);
        if (f >= 1.0f && f <= (float)NN) k = (int)f;
        else k = 70;
    }
    if (k > NN) k = NN;
    return k;
}

__device__ __forceinline__ unsigned okey(float f) {
    unsigned u = __float_as_uint(f);
    return (u & 0x80000000u) ? ~u : (u | 0x80000000u);
}
__device__ __forceinline__ float inv_okey(unsigned k) {
    unsigned u = (k & 0x80000000u) ? (k & 0x7FFFFFFFu) : ~k;
    return __uint_as_float(u);
}

// pack two fp32 -> two RNE bf16 in one u32 (a -> low, b -> high)  [r2/r3-proven]
__device__ __forceinline__ unsigned pk2bf(float a, float b) {
    unsigned ua = __float_as_uint(a); ua = (ua + 0x7FFFu + ((ua >> 16) & 1u)) >> 16;
    unsigned ub = __float_as_uint(b); ub = (ub + 0x7FFFu + ((ub >> 16) & 1u)) & 0xFFFF0000u;
    return (ua & 0xFFFFu) | ub;
}

__device__ __forceinline__ f32x4 mfma16(i32x4 a, i32x4 b, f32x4 c) {
    return __builtin_amdgcn_mfma_f32_16x16x32_bf16(
        __builtin_bit_cast(bf16x8, a), __builtin_bit_cast(bf16x8, b), c, 0, 0, 0);
}

__device__ __forceinline__ float sig_fast(float v)  { return 1.0f / (1.0f + __expf(-v)); }
__device__ __forceinline__ float tanh_fast(float v) { return 1.0f - 2.0f / (1.0f + __expf(2.0f * v)); }

// ---------------------------------------------------------------------------
// K0: swizzle Wv,Wu (fp32 [512][128]) into bf16 FRAGMENT-LANE order (r2-proven)
// ---------------------------------------------------------------------------
__global__ void k0_prep(const float* __restrict__ Wv, const float* __restrict__ Wu,
                        unsigned short* __restrict__ Wp)
{
    int i = blockIdx.x * 256 + threadIdx.x;    // 0 .. 131071
    int g   = i >> 16;
    int rem = i & 65535;                       // kd*128 + n
    int kd  = rem >> 7;
    int n   = rem & 127;
    float w = g ? Wu[rem] : Wv[rem];
    unsigned u = __float_as_uint(w);
    u = (u + 0x7FFFu + ((u >> 16) & 1u)) >> 16;
    int kt = kd >> 5, lg = (kd >> 3) & 3, j = kd & 7, nt = n >> 4, lr = n & 15;
    Wp[kt * 8192 + g * 4096 + nt * 512 + lg * 128 + lr * 8 + j] = (unsigned short)u;
}

// ---------------------------------------------------------------------------
// K1 (r10, verified, ~105us): operand-swapped MFMA acc = mfma(W, x, acc);
// d-reduction lives in registers (4 in-lane + 2 shfl). Verbatim from r10.
// ---------------------------------------------------------------------------
__global__ __launch_bounds__(512, 1)
void k1_mfma(const float* __restrict__ x, const unsigned short* __restrict__ Wp,
             const float* __restrict__ bv, const float* __restrict__ bu,
             const float* __restrict__ Wa, const float* __restrict__ ba,
             float* __restrict__ logits)
{
    __shared__ __align__(16) char lds[66560];  // buf0 32K | buf1 32K | sEp 1K

    const int t   = threadIdx.x;   // 0..511
    const int wid = t >> 6;        // 0..7
    const int l   = t & 63;
    const int lr  = l & 15;
    const int lg  = l >> 4;
    const int l7  = lr & 7;

    i32x4 Wreg[2][16];
    {
        const unsigned short* wb = Wp + wid * 512 + l * 8;
#pragma unroll
        for (int kt = 0; kt < 16; ++kt) {
#pragma unroll
            for (int g = 0; g < 2; ++g)
                Wreg[g][kt] = *(const i32x4*)(wb + kt * 8192 + g * 4096);
        }
    }

    const int dbase = wid * 16 + lg * 4;
    float bvR[4], buR[4], waR[4];
#pragma unroll
    for (int r = 0; r < 4; ++r) {
        bvR[r] = bv[dbase + r]; buR[r] = bu[dbase + r]; waR[r] = Wa[dbase + r];
    }
    const float ba0 = ba[0];

    const int c     = t & 127;
    const int r0    = t >> 7;        // 0..3
    const int chalf = c & 1;
    const int clog  = c >> 1;        // 0..63

    const size_t blk_row0 = (size_t)blockIdx.x * 1024;
    const float* xblk = x + blk_row0 * LDIM;
    float* sEp = (float*)(lds + 65536);   // [8 waves][32 rows]

    f32x4 acc[2][2];
    f32x4 xg[8];

#pragma unroll
    for (int i = 0; i < 8; ++i)
        xg[i] = *(const f32x4*)(xblk + (size_t)(i * 4 + r0) * LDIM + c * 4);
#pragma unroll
    for (int i = 0; i < 8; ++i) {
        int row = i * 4 + r0;
        u32x2 wv; wv.x = pk2bf(xg[i].x, xg[i].y); wv.y = pk2bf(xg[i].z, xg[i].w);
        *(u32x2*)(lds + row * 1024 + ((clog ^ (row & 7)) * 16) + chalf * 8) = wv;
    }
    __syncthreads();

    int p = 0;
    for (int j = 0; j < 32; ++j) {
        const bool has_next = (j < 31);
        if (has_next) {
            const float* xt = xblk + (size_t)(j + 1) * 32 * LDIM;
#pragma unroll
            for (int i = 0; i < 8; ++i)
                xg[i] = *(const f32x4*)(xt + (size_t)(i * 4 + r0) * LDIM + c * 4);
        }
#pragma unroll
        for (int g = 0; g < 2; ++g)
#pragma unroll
            for (int rf = 0; rf < 2; ++rf)
                acc[g][rf] = f32x4{0.f, 0.f, 0.f, 0.f};
        const char* Xb = lds + p * 32768;
#pragma unroll
        for (int kt = 0; kt < 16; ++kt) {
            i32x4 b0 = *(const i32x4*)(Xb + lr * 1024        + (((kt * 4 + lg) ^ l7) * 16));
            i32x4 b1 = *(const i32x4*)(Xb + (16 + lr) * 1024 + (((kt * 4 + lg) ^ l7) * 16));
            acc[0][0] = mfma16(Wreg[0][kt], b0, acc[0][0]);
            acc[1][0] = mfma16(Wreg[1][kt], b0, acc[1][0]);
            acc[0][1] = mfma16(Wreg[0][kt], b1, acc[0][1]);
            acc[1][1] = mfma16(Wreg[1][kt], b1, acc[1][1]);
        }
        if (has_next) {
            char* Xw = lds + (p ^ 1) * 32768;
#pragma unroll
            for (int i = 0; i < 8; ++i) {
                int row = i * 4 + r0;
                u32x2 wv; wv.x = pk2bf(xg[i].x, xg[i].y); wv.y = pk2bf(xg[i].z, xg[i].w);
                *(u32x2*)(Xw + row * 1024 + ((clog ^ (row & 7)) * 16) + chalf * 8) = wv;
            }
        }
#pragma unroll
        for (int rf = 0; rf < 2; ++rf) {
            float s = 0.f;
#pragma unroll
            for (int r = 0; r < 4; ++r) {
                float vv = tanh_fast(acc[0][rf][r] + bvR[r]);
                float uu = sig_fast (acc[1][rf][r] + buR[r]);
                s = fmaf(vv * uu, waR[r], s);
            }
            s += __shfl_xor(s, 16);
            s += __shfl_xor(s, 32);
            if (l < 16) sEp[wid * 32 + rf * 16 + l] = s;
        }
        __syncthreads();
        if (t < 32) {
            float s = ba0;
#pragma unroll
            for (int w2 = 0; w2 < 8; ++w2) s += sEp[w2 * 32 + t];
            logits[blk_row0 + j * 32 + t] = s;
        }
        __syncthreads();
        p ^= 1;
    }
}

// ---------------------------------------------------------------------------
// K3a (r11 rewrite): band-classify + softmax with 1024 threads/block ->
// 16 elements/thread stays REGISTER-RESIDENT (raw[16]+kk[16]=32 VGPR; the
// r8/r10 version's 64-elem arrays spilled at VGPR=64 and cost ~150-500us).
// Same proven algorithm: binary-search k-th largest masked logit, classify
// definite-in / band, fused masked softmax (denominators cancel).
// ---------------------------------------------------------------------------
__global__ __launch_bounds__(1024, 1)
void k3a_band_softmax(float* __restrict__ A, const float* __restrict__ mask,
                      const int* __restrict__ kp, int* __restrict__ idxWS,
                      int* __restrict__ candIdx, int* __restrict__ counts)
{
    __shared__ float sredf[16];
    __shared__ int   sredi[16];
    __shared__ int sIn, sCand;
    const int b = blockIdx.x;
    const int t = threadIdx.x;     // 0..1023
    const int w = t >> 6;          // 0..15
    int k = get_k(kp); if (k > KCAP) k = KCAP;
    float* Ab = A + (size_t)b * NN;
    const float* mb = mask + (size_t)b * NN;

    float raw[16]; unsigned mbits = 0u;
#pragma unroll
    for (int j = 0; j < 16; ++j) {
        int i = t + j * 1024;
        raw[j] = Ab[i];
        if (mb[i] > 0.0f) mbits |= (1u << j);
    }
    unsigned kk[16];
#pragma unroll
    for (int j = 0; j < 16; ++j) {
        float v = ((mbits >> j) & 1) ? raw[j] : -3.0e38f;
        kk[j] = okey(v);
    }

    // binary search: largest T with count(key >= T) >= k
    unsigned lo = 0u, hi = 0xFFFFFFFFu;
    while (lo < hi) {
        unsigned span = hi - lo;
        unsigned mid = lo + (span >> 1) + (span & 1u);
        int c = 0;
#pragma unroll
        for (int j = 0; j < 16; ++j) c += (kk[j] >= mid) ? 1 : 0;
#pragma unroll
        for (int m2 = 1; m2 < 64; m2 <<= 1) c += __shfl_xor(c, m2);
        __syncthreads();
        if ((t & 63) == 0) sredi[w] = c;
        __syncthreads();
        c = 0;
#pragma unroll
        for (int w2 = 0; w2 < 16; ++w2) c += sredi[w2];
        if (c >= k) lo = mid; else hi = mid - 1;
    }
    const float tv = inv_okey(lo);

    if (t == 0) { sIn = 0; sCand = 0; }
    __syncthreads();
    const float hiB = tv + DELTA, loB = tv - DELTA;
#pragma unroll
    for (int j = 0; j < 16; ++j) {
        int i = t + j * 1024;
        float v = ((mbits >> j) & 1) ? raw[j] : -3.0e38f;
        if (v > hiB)       { int p = atomicAdd(&sIn, 1);   if (p < KCAP) idxWS[b * KCAP + p] = i; }
        else if (v >= loB) { int p = atomicAdd(&sCand, 1); if (p < CCAP) candIdx[b * CCAP + p] = i; }
    }

    // fused softmax: M = unmasked max (matches reference softmax axis=1)
    float mx = -INFINITY;
#pragma unroll
    for (int j = 0; j < 16; ++j) mx = fmaxf(mx, raw[j]);
#pragma unroll
    for (int m2 = 1; m2 < 64; m2 <<= 1) mx = fmaxf(mx, __shfl_xor(mx, m2));
    __syncthreads();
    if ((t & 63) == 0) sredf[w] = mx;
    __syncthreads();
    mx = sredf[0];
#pragma unroll
    for (int w2 = 1; w2 < 16; ++w2) mx = fmaxf(mx, sredf[w2]);

    float sAll = 0.f, sM = 0.f;
#pragma unroll
    for (int j = 0; j < 16; ++j) {
        float e = __expf(raw[j] - mx);
        sAll += e;
        if ((mbits >> j) & 1) sM += e;
    }
#pragma unroll
    for (int m2 = 1; m2 < 64; m2 <<= 1) sAll += __shfl_xor(sAll, m2);
    __syncthreads();
    if ((t & 63) == 0) sredf[w] = sAll;
    __syncthreads();
    sAll = 0.f;
#pragma unroll
    for (int w2 = 0; w2 < 16; ++w2) sAll += sredf[w2];
#pragma unroll
    for (int m2 = 1; m2 < 64; m2 <<= 1) sM += __shfl_xor(sM, m2);
    __syncthreads();
    if ((t & 63) == 0) sredf[w] = sM;
    __syncthreads();
    sM = 0.f;
#pragma unroll
    for (int w2 = 0; w2 < 16; ++w2) sM += sredf[w2];

    const float inv = 1.0f / (sM + EPSV * sAll);
#pragma unroll
    for (int j = 0; j < 16; ++j) {
        int i = t + j * 1024;
        float e = __expf(raw[j] - mx);
        Ab[i] = ((mbits >> j) & 1) ? e * inv : 0.0f;
    }
    if (t == 0) {
        int m1 = sIn;   if (m1 > k)    m1 = k;
        int cc = sCand; if (cc > CCAP) cc = CCAP;
        counts[b * 4]     = m1;
        counts[b * 4 + 1] = cc;
    }
}

// ---------------------------------------------------------------------------
// K3b: exact fp32 logits for band candidates, row-batched (verbatim r6-r8).
// ---------------------------------------------------------------------------
__global__ void k3b_exact(const float* __restrict__ x,
                          const float* __restrict__ Wv, const float* __restrict__ bv,
                          const float* __restrict__ Wu, const float* __restrict__ bu,
                          const float* __restrict__ Wa, const float* __restrict__ ba,
                          const int* __restrict__ candIdx, const int* __restrict__ counts,
                          float* __restrict__ candVal)
{
    __shared__ __align__(16) float sx[ROWB][LDIM];   // 16 KB
    __shared__ float sred[2][ROWB];
    const int b = blockIdx.x;
    const int t = threadIdx.x;          // 0..127
    const int w = t >> 6;
    const int cnt = counts[b * 4 + 1];
    const float bvt = bv[t], but = bu[t], wat = Wa[t], ba0 = ba[0];

    for (int base = blockIdx.y * ROWB; base < cnt; base += gridDim.y * ROWB) {
        const int nr = min(ROWB, cnt - base);
        for (int r = 0; r < nr; ++r) {
            const int row = candIdx[b * CCAP + base + r];
            ((f32x4*)&sx[r][0])[t] =
                ((const f32x4*)(x + ((size_t)b * NN + (size_t)row) * LDIM))[t];
        }
        __syncthreads();

        float dv[ROWB], du[ROWB];
#pragma unroll
        for (int r = 0; r < ROWB; ++r) { dv[r] = bvt; du[r] = but; }
#pragma unroll 4
        for (int ll = 0; ll < LDIM; ++ll) {
            const float wvl = Wv[ll * DDIM + t];
            const float wul = Wu[ll * DDIM + t];
#pragma unroll
            for (int r = 0; r < ROWB; ++r) {
                const float xv = sx[r][ll];
                dv[r] = fmaf(xv, wvl, dv[r]);
                du[r] = fmaf(xv, wul, du[r]);
            }
        }
#pragma unroll
        for (int r = 0; r < ROWB; ++r) {
            float c = tanhf(dv[r]) * (1.0f / (1.0f + expf(-du[r]))) * wat;
            c += __shfl_xor(c, 1);  c += __shfl_xor(c, 2);
            c += __shfl_xor(c, 4);  c += __shfl_xor(c, 8);
            c += __shfl_xor(c, 16); c += __shfl_xor(c, 32);
            if ((t & 63) == 0) sred[w][r] = c;
        }
        __syncthreads();
        if (t < nr) candVal[b * CCAP + base + t] = sred[0][t] + sred[1][t] + ba0;
        __syncthreads();
    }
}

// ---------------------------------------------------------------------------
// K34: select + rank-sort + gather + mean-pool + MLP + argmax (verbatim r8).
// ---------------------------------------------------------------------------
__global__ void k34_select_final(const float* __restrict__ x, const int* __restrict__ kp,
                                 const int* __restrict__ candIdx, const float* __restrict__ candVal,
                                 const int* __restrict__ counts, const int* __restrict__ idxWS,
                                 const float* __restrict__ W1, const float* __restrict__ b1,
                                 const float* __restrict__ W2, const float* __restrict__ b2,
                                 float* __restrict__ Yprob, float* __restrict__ Yhat)
{
    __shared__ u64 keys[CCAP];
    __shared__ int sIdx[KCAP];
    __shared__ int sFinal[KCAP];
    __shared__ int sPos;
    __shared__ float sPooled[LDIM];
    __shared__ float sH[HIDD];
    __shared__ float sY[4];
    const int b = blockIdx.x;
    const int t = threadIdx.x;
    int k = get_k(kp); if (k > KCAP) k = KCAP;
    const int m1  = counts[b * 4];
    const int cnt = counts[b * 4 + 1];
    int need = k - m1; if (need < 0) need = 0; if (need > cnt) need = cnt;

    for (int i = t; i < cnt; i += 256)
        keys[i] = (((u64)okey(candVal[b * CCAP + i])) << 14)
                | (u64)(16383 - candIdx[b * CCAP + i]);
    if (t < m1) sIdx[t] = idxWS[b * KCAP + t];
    if (t == 0) sPos = 0;
    if (t < KCAP) sFinal[t] = 0;
    __syncthreads();
    for (int i = t; i < cnt; i += 256) {
        u64 mk = keys[i];
        int rank = 0;
        for (int j = 0; j < cnt; ++j) rank += (keys[j] > mk) ? 1 : 0;
        if (rank < need) { int p = atomicAdd(&sPos, 1); sIdx[m1 + p] = candIdx[b * CCAP + i]; }
    }
    __syncthreads();
    int tot = m1 + need; if (tot > k) tot = k;
    if (t < tot) {
        int myv = sIdx[t];
        int rank = 0;
        for (int e = 0; e < tot; ++e) rank += (sIdx[e] < myv) ? 1 : 0;
        sFinal[rank] = myv;
    }
    __syncthreads();

    float a0 = 0.0f, a1 = 0.0f;
    {
        int j = 0;
        for (; j + 8 <= k; j += 8) {
            float t0[8], t1[8];
#pragma unroll
            for (int u2 = 0; u2 < 8; ++u2) {
                const float* xr = x + ((size_t)b * NN + (size_t)sFinal[j + u2]) * LDIM;
                t0[u2] = xr[t]; t1[u2] = xr[t + 256];
            }
#pragma unroll
            for (int u2 = 0; u2 < 8; ++u2) { a0 += t0[u2]; a1 += t1[u2]; }
        }
        for (; j < k; ++j) {
            const float* xr = x + ((size_t)b * NN + (size_t)sFinal[j]) * LDIM;
            a0 += xr[t]; a1 += xr[t + 256];
        }
    }
    const float invk = 1.0f / (float)k;
    sPooled[t]       = a0 * invk;
    sPooled[t + 256] = a1 * invk;
    __syncthreads();

    if (t < HIDD) {
        float acc = b1[t];
        for (int ll = 0; ll < LDIM; ++ll) acc = fmaf(sPooled[ll], W1[ll * HIDD + t], acc);
        sH[t] = fmaxf(acc, 0.0f);
    }
    __syncthreads();
    if (t < NCLS) {
        float y = b2[t];
        for (int hh = 0; hh < HIDD; ++hh) y = fmaf(sH[hh], W2[hh * NCLS + t], y);
        Yprob[b * NCLS + t] = y;
        sY[t] = y;
    }
    __syncthreads();
    if (t == 0) {
        int am = 0; float bst = sY[0];
        if (sY[1] > bst) { bst = sY[1]; am = 1; }
        if (sY[2] > bst) { bst = sY[2]; am = 2; }
        Yhat[b] = (float)am;
    }
}

// ---------------------------------------------------------------------------
extern "C" void kernel_launch(void* const* d_in, const int* in_sizes, int n_in,
                              void* d_out, int out_size, void* d_ws, size_t ws_size,
                              hipStream_t stream)
{
    const float* x    = (const float*)d_in[0];
    const float* mask = (const float*)d_in[1];
    const float* Wv   = (const float*)d_in[2];
    const float* bv   = (const float*)d_in[3];
    const float* Wu   = (const float*)d_in[4];
    const float* bu   = (const float*)d_in[5];
    const float* Wa   = (const float*)d_in[6];
    const float* ba   = (const float*)d_in[7];
    const float* W1   = (const float*)d_in[8];
    const float* b1   = (const float*)d_in[9];
    const float* W2   = (const float*)d_in[10];
    const float* b2   = (const float*)d_in[11];
    const int*   kp   = (const int*)d_in[12];

    float* out   = (float*)d_out;
    float* Yprob = out;        // [16,3] = 48
    float* Yhat  = out + 48;   // [16]
    float* A     = out + 64;   // [16,16384]  (logits first, softmax in-place)

    char* wsb = (char*)d_ws;
    unsigned short* Wp = (unsigned short*)wsb;        // 262144 B
    int*   idxWS   = (int*)  (wsb + 262144);          // 16 KB
    int*   candIdx = (int*)  (wsb + 278528);          // 64 KB
    float* candVal = (float*)(wsb + 344064);          // 64 KB
    int*   counts  = (int*)  (wsb + 409600);          // 256 B

    k0_prep  <<<512, 256, 0, stream>>>(Wv, Wu, Wp);
    k1_mfma  <<<256, 512, 0, stream>>>(x, Wp, bv, bu, Wa, ba, A);
    k3a_band_softmax<<<NB, 1024, 0, stream>>>(A, mask, kp, idxWS, candIdx, counts);
    k3b_exact<<<dim3(NB, 32), 128, 0, stream>>>(x, Wv, bv, Wu, bu, Wa, ba,
                                                candIdx, counts, candVal);
    k34_select_final<<<NB, 256, 0, stream>>>(x, kp, candIdx, candVal, counts, idxWS,
                                             W1, b1, W2, b2, Yprob, Yhat);
}